// Round 4
// baseline (1566.747 us; speedup 1.0000x reference)
//
#include <hip/hip_runtime.h>

namespace {

constexpr float C2  = 0.2f;   // DT/DX^2 (stencil coefficient)
constexpr float DTC = 0.2f;   // DT
constexpr float IDT = 5.0f;   // 1/DT

#define AQ  __ATOMIC_ACQUIRE
#define RLX __ATOMIC_RELAXED
#define REL __ATOMIC_RELEASE
#define WG  __HIP_MEMORY_SCOPE_WORKGROUP
#define AG  __HIP_MEMORY_SCOPE_AGENT

// Zero the 544 sync flags each launch (stream-ordered before the main
// kernel, so graph replay always starts from a clean flag state).
__global__ void zero_flags(int* flags) {
    if (threadIdx.x < 544) flags[threadIdx.x] = 0;
}

// R4: TRUE spatial split -- no redundant compute. 256 blocks = 32 batches x
// 8 parts; block (b,part) owns global rows [8*part, 8*part+8), wave w = row
// 8*part+w, lane = y. 1 cell/thread. Rounds 0-3 all ran the full 4-field
// scan redundantly in every block (8x inflated VALU ~70us/CU + LDS ~80us/CU,
// additive -> 155-180us floor). Here per-CU VALU ~9us, LDS ~15us, and the
// wall becomes the irreducible 233MB output drain (~55-70us at write BW).
//
// Cross-block per step: 2 boundary rows (float4 {xi,f4,f5,f6} per cell) +
// row-62 xi (for the x==0 I2 path), through d_ws / L2. Single-writer
// monotone flags, release/acquire at agent scope. Halo slots double-buffer
// by t&1; overwrite of slot (t+1)&1 (holding state t-1) is safe because the
// writer has already spun on the consumer's progress flag >= t this step.
// In-block rows go through LDS with the R3-proven per-wave chain flags (no
// barrier -> interior waves never wait on the edge waves' global latency).
// Cooperative launch guarantees all 256 blocks are co-resident.
__global__ __launch_bounds__(512, 2)
void fused_scan(const float* __restrict__ W, float* __restrict__ out,
                float4* __restrict__ haloU, float4* __restrict__ haloD,
                float* __restrict__ r62buf,
                int* __restrict__ flagU, int* __restrict__ flagD,
                int* __restrict__ flag62) {
    __shared__ float sst[2][8][4][64];          // [slot][local row][field][y]
    __shared__ __align__(16) float spk[8][448]; // per-wave output repack
    __shared__ int wdone[8];   // in-block: latest state written to LDS
    __shared__ int rdone[8];   // in-block: latest state whose reads finished

    const int tid  = threadIdx.x;
    const int b    = blockIdx.x & 31;        // same-XCD mapping kept (R1 win)
    const int part = blockIdx.x >> 5;        // 0..7
    const int w    = tid >> 6;               // local row / wave
    const int y    = tid & 63;               // lane = y
    const int x    = (part << 3) + w;        // global row

    const int pm = (part + 7) & 7;
    const int pp = (part + 1) & 7;

    const bool isW0    = (w == 0);
    const bool isW7    = (w == 7);
    const bool is62pub = (part == 7) && (w == 6);   // owns global row 62
    const bool isX0    = (part == 0) && (w == 0);   // x==0: I2 reads row 62
    const bool xedge   = (x == 0) || (x == 63);
    const bool corner  = xedge && ((y == 0) || (y == 63));

    const int laneYm = (y + 63) & 63;
    const int laneYp = (y + 1) & 63;

    if (tid < 8) { wdone[tid] = 0; rdone[tid] = -1; }
    __syncthreads();   // only block-wide barrier (flag init)

    const float* Wb = W   + (size_t)b * 64 * 4096;
    float*       oB = out + (size_t)b * 64 * 4096 * 7;

    const int fU  = b * 8 + part;   // my flag index
    const int fUo = b * 8 + pp;     // up-flag I consume (wave 7)
    const int fDo = b * 8 + pm;     // down-flag I consume (wave 0)

    float cxi = 0.f, c4 = 0.f, c5 = 0.f, c6 = 0.f, xprev = 0.f, wprev = 0.f;
    float wt = Wb[x * 64 + y];      // W at t=0

    int cb = 0;   // slot holding state t
    for (int t = 0; t < 64; ++t) {
        // ---- W prefetch for t+1 (hidden under the whole iteration; only
        //      edge waves' release-drain ever waits on it) ----
        float wnext = 0.f;
        if (t < 63) wnext = Wb[(t + 1) * 4096 + x * 64 + y];

        const float dw = (t == 0) ? 0.f : (wt - wprev) * IDT;
        wprev = wt;

        // ---- acquire neighbor rows (state t) ----
        float nmv[4], npv[4], xi2;
        if (t == 0) {   // state 0 is all zeros: no reads, no spins
            nmv[0]=nmv[1]=nmv[2]=nmv[3]=0.f;
            npv[0]=npv[1]=npv[2]=npv[3]=0.f;
            xi2 = 0.f;
            __hip_atomic_store(&rdone[w], 0, RLX, WG);
        } else {
            if (w > 0) while (__hip_atomic_load(&wdone[w-1], AQ, WG) < t) {}
            if (w < 7) while (__hip_atomic_load(&wdone[w+1], AQ, WG) < t) {}
            if (isW0) while (__hip_atomic_load(&flagD[fDo], AQ, AG) < t) __builtin_amdgcn_s_sleep(1);
            if (isW7) while (__hip_atomic_load(&flagU[fUo], AQ, AG) < t) __builtin_amdgcn_s_sleep(1);
            if (isX0) while (__hip_atomic_load(&flag62[b], AQ, AG) < t) __builtin_amdgcn_s_sleep(1);

            if (w > 0) {
                nmv[0] = sst[cb][w-1][0][y]; nmv[1] = sst[cb][w-1][1][y];
                nmv[2] = sst[cb][w-1][2][y]; nmv[3] = sst[cb][w-1][3][y];
            } else {   // row x-1 = part pm's row 8pm+7 (periodic in x)
                float4 h = haloD[(fDo * 2 + cb) * 64 + y];
                nmv[0] = h.x; nmv[1] = h.y; nmv[2] = h.z; nmv[3] = h.w;
            }
            if (w < 7) {
                npv[0] = sst[cb][w+1][0][y]; npv[1] = sst[cb][w+1][1][y];
                npv[2] = sst[cb][w+1][2][y]; npv[3] = sst[cb][w+1][3][y];
            } else {   // row x+1 = part pp's row 8pp
                float4 h = haloU[(fUo * 2 + cb) * 64 + y];
                npv[0] = h.x; npv[1] = h.y; npv[2] = h.z; npv[3] = h.w;
            }
            // I2 source: row x-1 for x>0 (== nm), row 62 for x==0
            xi2 = isX0 ? r62buf[(b * 2 + cb) * 64 + y] : nmv[0];
            asm volatile("s_waitcnt lgkmcnt(0)" ::: "memory");
            __hip_atomic_store(&rdone[w], t, RLX, WG);
        }

        // snapshot output values for time t (before state advances)
        const float o1 = cxi;
        const float o2 = (t == 0) ? 0.f : -xprev;   // I1; t=0 fixed post-loop
        const float o3 = -xi2;                      // I2
        const float o4 = c4, o5 = c5, o6 = c6;

        // ---- compute + publish state t+1 ----
        if (t < 63) {
            const float g4 = dw * cxi;          // dW * I_xi
            const float g5 = cxi * cxi;         // I_xi^2
            const float g6 = xprev * xi2;       // I1*I2 = (-xprev)(-xi2)
            xprev = cxi;

            float cf[4] = {cxi, c4, c5, c6};
            const float gg[4] = {dw, g4, g5, g6};
            float nf[4];
            #pragma unroll
            for (int f = 0; f < 4; ++f) {
                const float ym = __shfl(cf[f], laneYm, 64);   // y periodic
                const float yp = __shfl(cf[f], laneYp, 64);
                float lap = nmv[f] + npv[f] + ym + yp - 4.f * cf[f];
                if (corner) lap = 0.f;                        // grid corners
                nf[f] = cf[f] + C2 * lap + gg[f] * DTC;
            }

            const int ns = cb ^ 1;
            // in-block: neighbors consumed state t-1 from slot ns
            if (w > 0) while (__hip_atomic_load(&rdone[w-1], AQ, WG) < t - 1) {}
            if (w < 7) while (__hip_atomic_load(&rdone[w+1], AQ, WG) < t - 1) {}
            sst[ns][w][0][y] = nf[0]; sst[ns][w][1][y] = nf[1];
            sst[ns][w][2][y] = nf[2]; sst[ns][w][3][y] = nf[3];
            asm volatile("s_waitcnt lgkmcnt(0)" ::: "memory");
            __hip_atomic_store(&wdone[w], t + 1, RLX, WG);

            // cross-block publishes (overwrite-safety: see header comment)
            if (isW0) {
                haloU[(fU * 2 + ns) * 64 + y] = make_float4(nf[0], nf[1], nf[2], nf[3]);
                if (y == 0) __hip_atomic_store(&flagU[fU], t + 1, REL, AG);
            }
            if (isW7) {
                haloD[(fU * 2 + ns) * 64 + y] = make_float4(nf[0], nf[1], nf[2], nf[3]);
                if (y == 0) __hip_atomic_store(&flagD[fU], t + 1, REL, AG);
            }
            if (is62pub) {
                // part 0 published flagU>=t only after consuming r62[t-1]
                while (__hip_atomic_load(&flagU[b * 8 + 0], AQ, AG) < t) __builtin_amdgcn_s_sleep(1);
                r62buf[(b * 2 + ns) * 64 + y] = nf[0];
                if (y == 0) __hip_atomic_store(&flag62[b], t + 1, REL, AG);
            }

            cxi = nf[0]; c4 = nf[1]; c5 = nf[2]; c6 = nf[3];
            cb = ns;
        }

        // ---- store outputs for time t: repack 7 ch -> float4 via LDS
        //      (7 scalar stores would be 7x the store transactions) ----
        {
            float* pk = &spk[w][0];
            pk[y * 7 + 0] = dw;  pk[y * 7 + 1] = o1; pk[y * 7 + 2] = o2;
            pk[y * 7 + 3] = o3;  pk[y * 7 + 4] = o4; pk[y * 7 + 5] = o5;
            pk[y * 7 + 6] = o6;
            // in-wave RAW on spk: compiler inserts the lgkmcnt
            float4* gdst = (float4*)(oB + (size_t)(t * 4096 + x * 64) * 7);
            float4 v0 = *(float4*)&pk[4 * y];
            gdst[y] = v0;
            if (y < 48) {
                float4 v1 = *(float4*)&pk[256 + 4 * y];
                gdst[64 + y] = v1;
            }
        }

        wt = wnext;
    }

    // ch2 fixup at t=0: I1[0] = -I_xi[62] (xprev after the loop = state 62;
    // same thread overwrites its own earlier store; wt-load vmcnt waits in
    // between guarantee ordering)
    oB[(size_t)(x * 64 + y) * 7 + 2] = -xprev;
}

} // namespace

extern "C" void kernel_launch(void* const* d_in, const int* in_sizes, int n_in,
                              void* d_out, int out_size, void* d_ws, size_t ws_size,
                              hipStream_t stream) {
    const float* W  = (const float*)d_in[0];
    float* out      = (float*)d_out;

    char* ws = (char*)d_ws;
    float4* haloU  = (float4*)ws;                           // 512 KB
    float4* haloD  = (float4*)(ws + 512 * 1024);            // 512 KB
    float*  r62    = (float*)(ws + 1024 * 1024);            // 16 KB
    int*    flagU  = (int*)(ws + 1024 * 1024 + 16 * 1024);  // 256 ints
    int*    flagD  = flagU + 256;                           // 256 ints
    int*    flag62 = flagD + 256;                           // 32 ints

    hipLaunchKernelGGL(zero_flags, dim3(1), dim3(576), 0, stream, flagU);

    void* args[] = {(void*)&W, (void*)&out, (void*)&haloU, (void*)&haloD,
                    (void*)&r62, (void*)&flagU, (void*)&flagD, (void*)&flag62};
    hipLaunchCooperativeKernel((const void*)fused_scan, dim3(256), dim3(512),
                               args, 0, stream);
}